// Round 1
// baseline (2359.850 us; speedup 1.0000x reference)
//
#include <hip/hip_runtime.h>
#include <stdint.h>

typedef __attribute__((ext_vector_type(8))) short  short8;
typedef __attribute__((ext_vector_type(4))) float  f32x4;

static constexpr float BETA = 0.95f;

// ---------- bf16 helpers (bit-level, no __hip_bfloat16 dependency) ----------
__device__ __forceinline__ unsigned short f2bf(float f) {
  uint32_t u = __float_as_uint(f);
  uint32_t r = (u + 0x7fffu + ((u >> 16) & 1u)) >> 16;   // RNE
  return (unsigned short)r;
}
__device__ __forceinline__ float bf2f(unsigned short s) {
  return __uint_as_float((uint32_t)s << 16);
}

// ---------- async global->LDS (16B per lane, wave-uniform LDS base) ----------
__device__ __forceinline__ void gload16(const void* g, void* l) {
  __builtin_amdgcn_global_load_lds(
      (const __attribute__((address_space(1))) uint32_t*)g,
      (__attribute__((address_space(3))) uint32_t*)l, 16, 0, 0);
}

// ---------- conversion kernels ----------
// x: [B=4096, T=5, 1024] f32  ->  xb: [T][B][1024] bf16
__global__ void cvt_x_k(const float* __restrict__ x, unsigned short* __restrict__ xb) {
  int i = blockIdx.x * blockDim.x + threadIdx.x;   // 4096*5*128 threads
  int k8 = i & 127;
  int bt = i >> 7;                                  // b*5 + t
  int b = bt / 5, t = bt - b * 5;
  const f32x4* s = (const f32x4*)(x + (size_t)bt * 1024 + (size_t)k8 * 8);
  unsigned short* d = xb + ((size_t)t * 4096 + b) * 1024 + (size_t)k8 * 8;
  f32x4 a = s[0], c = s[1];
  short8 o;
#pragma unroll
  for (int j = 0; j < 4; ++j) { o[j] = (short)f2bf(a[j]); o[4 + j] = (short)f2bf(c[j]); }
  *(short8*)d = o;
}

__global__ void cvt_w_k(const float* __restrict__ src, unsigned short* __restrict__ dst, int n8) {
  int i = blockIdx.x * blockDim.x + threadIdx.x;
  if (i >= n8) return;
  const f32x4* s = (const f32x4*)src + (size_t)i * 2;
  f32x4 a = s[0], c = s[1];
  short8 o;
#pragma unroll
  for (int j = 0; j < 4; ++j) { o[j] = (short)f2bf(a[j]); o[4 + j] = (short)f2bf(c[j]); }
  *(short8*)(dst + (size_t)i * 8) = o;
}

// ---------- fused GEMM (C = A @ W^T + b) + LIF epilogue ----------
// A: [M,K] bf16 row-major (K contiguous), W: [N,K] bf16 row-major.
// mem: [M,N] f32 state. sbuf: [M,N] bf16 spikes (read prev / write new).
// LAYER==3: accumulate spike into outacc (write at FIRST, add after).
template <bool FIRST, int LAYER>
__global__ __launch_bounds__(256, 2) void gemm_lif(
    const unsigned short* __restrict__ A, const unsigned short* __restrict__ W,
    const float* __restrict__ bias,
    float* __restrict__ mem, unsigned short* __restrict__ sbuf,
    float* __restrict__ outacc,
    int M, int N, int K)
{
  __shared__ __align__(16) unsigned short As[2][128 * 32];
  __shared__ __align__(16) unsigned short Bs[2][128 * 32];

  const int tid  = threadIdx.x;
  const int wid  = tid >> 6;
  const int lane = tid & 63;
  const int bm = blockIdx.x, bn = blockIdx.y;
  const int wr = wid >> 1, wc = wid & 1;
  const int krow = lane >> 2;            // row within a 16-row staging chunk
  const int kcol = (lane & 3) << 3;      // 0,8,16,24 (bf16 elems)

  f32x4 acc[4][4];
#pragma unroll
  for (int m = 0; m < 4; ++m)
#pragma unroll
    for (int n = 0; n < 4; ++n) acc[m][n] = (f32x4){0.f, 0.f, 0.f, 0.f};

  const unsigned short* gA = A + (size_t)bm * 128 * K;
  const unsigned short* gB = W + (size_t)bn * 128 * K;
  const int r0 = wid * 32;  // each wave stages 32 rows of A and of B (2 chunks of 16)

  auto stage = [&](int buf, int kt) {
    const unsigned short* ga = gA + (size_t)kt * 32;
    const unsigned short* gb = gB + (size_t)kt * 32;
#pragma unroll
    for (int c = 0; c < 2; ++c) {
      int row0 = r0 + c * 16;
      // per-lane global src; wave-uniform LDS dest (HW: base + lane*16B -> linear [128][32])
      gload16(ga + (size_t)(row0 + krow) * K + kcol, &As[buf][row0 * 32]);
      gload16(gb + (size_t)(row0 + krow) * K + kcol, &Bs[buf][row0 * 32]);
    }
  };

  auto compute = [&](int buf) {
    short8 af[4], bfr[4];
    const int ar = wr * 64 + (lane & 15);
    const int br = wc * 64 + (lane & 15);
    const int kseg = (lane >> 4) * 8;
#pragma unroll
    for (int m = 0; m < 4; ++m)
      af[m] = *(const short8*)&As[buf][(ar + m * 16) * 32 + kseg];
#pragma unroll
    for (int n = 0; n < 4; ++n)
      bfr[n] = *(const short8*)&Bs[buf][(br + n * 16) * 32 + kseg];
#pragma unroll
    for (int m = 0; m < 4; ++m)
#pragma unroll
      for (int n = 0; n < 4; ++n)
        acc[m][n] = __builtin_amdgcn_mfma_f32_16x16x32_bf16(af[m], bfr[n], acc[m][n], 0, 0, 0);
  };

  const int nkt = K >> 5;
  stage(0, 0);
  __syncthreads();
  int cur = 0;
  for (int kt = 1; kt < nkt; ++kt) {
    stage(cur ^ 1, kt);       // prefetch next tile (drained by the barrier below)
    compute(cur);
    __syncthreads();
    cur ^= 1;
  }
  compute(cur);

  // ---- LIF epilogue. C/D layout: col = lane&15, row = (lane>>4)*4 + reg ----
  const int crow0 = bm * 128 + wr * 64;
  const int ccol0 = bn * 128 + wc * 64;
#pragma unroll
  for (int m = 0; m < 4; ++m) {
#pragma unroll
    for (int n = 0; n < 4; ++n) {
      const int col = ccol0 + n * 16 + (lane & 15);
      const float bcol = bias[col];
#pragma unroll
      for (int j = 0; j < 4; ++j) {
        const int row = crow0 + m * 16 + (lane >> 4) * 4 + j;
        const size_t idx = (size_t)row * N + col;
        const float curv = acc[m][n][j] + bcol;
        const float mold = FIRST ? 0.f : mem[idx];
        const float sprv = FIRST ? 0.f : bf2f(sbuf[idx]);
        const float mnew = BETA * mold + curv - sprv;   // reset_mechanism='subtract', THRESH=1
        mem[idx] = mnew;
        const float s = (mnew - 1.0f) > 0.f ? 1.f : 0.f;
        sbuf[idx] = f2bf(s);
        if (LAYER == 3) outacc[idx] = FIRST ? s : (outacc[idx] + s);
      }
    }
  }
}

// ---------- host ----------
extern "C" void kernel_launch(void* const* d_in, const int* in_sizes, int n_in,
                              void* d_out, int out_size, void* d_ws, size_t ws_size,
                              hipStream_t stream)
{
  const float* x  = (const float*)d_in[0];
  const float* W1 = (const float*)d_in[1];
  const float* b1 = (const float*)d_in[2];
  const float* W2 = (const float*)d_in[3];
  const float* b2 = (const float*)d_in[4];
  const float* W3 = (const float*)d_in[5];
  const float* b3 = (const float*)d_in[6];
  float* out = (float*)d_out;

  char* p = (char*)d_ws;
  auto wsalloc = [&](size_t bytes) { char* r = p; p += (bytes + 255) & ~(size_t)255; return r; };
  unsigned short* xb   = (unsigned short*)wsalloc((size_t)5 * 4096 * 1024 * 2);
  unsigned short* W1b  = (unsigned short*)wsalloc((size_t)4096 * 1024 * 2);
  unsigned short* W2b  = (unsigned short*)wsalloc((size_t)4096 * 4096 * 2);
  unsigned short* W3b  = (unsigned short*)wsalloc((size_t)1024 * 4096 * 2);
  unsigned short* s1   = (unsigned short*)wsalloc((size_t)4096 * 4096 * 2);
  unsigned short* s2   = (unsigned short*)wsalloc((size_t)4096 * 4096 * 2);
  unsigned short* s3   = (unsigned short*)wsalloc((size_t)4096 * 1024 * 2);
  float* mem1 = (float*)wsalloc((size_t)4096 * 4096 * 4);
  float* mem2 = (float*)wsalloc((size_t)4096 * 4096 * 4);
  float* mem3 = (float*)wsalloc((size_t)4096 * 1024 * 4);

  // conversions (re-done every call; inputs restored by harness each launch)
  cvt_x_k<<<dim3(4096 * 5 * 128 / 256), dim3(256), 0, stream>>>(x, xb);
  cvt_w_k<<<dim3(4096 * 1024 / 8 / 256), dim3(256), 0, stream>>>(W1, W1b, 4096 * 1024 / 8);
  cvt_w_k<<<dim3(4096 * 4096 / 8 / 256), dim3(256), 0, stream>>>(W2, W2b, 4096 * 4096 / 8);
  cvt_w_k<<<dim3(1024 * 4096 / 8 / 256), dim3(256), 0, stream>>>(W3, W3b, 1024 * 4096 / 8);

  const dim3 blk(256);
  const dim3 g12(32, 32), g3(32, 8);

  // t = 0 (mem=0, s_prev=0 -> no state reads; out is written, not accumulated)
  gemm_lif<true, 1><<<g12, blk, 0, stream>>>(xb, W1b, b1, mem1, s1, nullptr, 4096, 4096, 1024);
  gemm_lif<true, 2><<<g12, blk, 0, stream>>>(s1, W2b, b2, mem2, s2, nullptr, 4096, 4096, 4096);
  gemm_lif<true, 3><<<g3,  blk, 0, stream>>>(s2, W3b, b3, mem3, s3, out,     4096, 1024, 4096);
  for (int t = 1; t < 5; ++t) {
    gemm_lif<false, 1><<<g12, blk, 0, stream>>>(xb + (size_t)t * 4096 * 1024, W1b, b1, mem1, s1, nullptr, 4096, 4096, 1024);
    gemm_lif<false, 2><<<g12, blk, 0, stream>>>(s1, W2b, b2, mem2, s2, nullptr, 4096, 4096, 4096);
    gemm_lif<false, 3><<<g3,  blk, 0, stream>>>(s2, W3b, b3, mem3, s3, out,     4096, 1024, 4096);
  }
}

// Round 2
// 2323.962 us; speedup vs baseline: 1.0154x; 1.0154x over previous
//
#include <hip/hip_runtime.h>
#include <stdint.h>

typedef __attribute__((ext_vector_type(8))) short  short8;
typedef __attribute__((ext_vector_type(4))) float  f32x4;

static constexpr float BETA = 0.95f;

// ---------- bf16 helpers ----------
__device__ __forceinline__ unsigned short f2bf(float f) {
  uint32_t u = __float_as_uint(f);
  uint32_t r = (u + 0x7fffu + ((u >> 16) & 1u)) >> 16;   // RNE
  return (unsigned short)r;
}
__device__ __forceinline__ float bf2f(unsigned short s) {
  return __uint_as_float((uint32_t)s << 16);
}

// ---------- async global->LDS (16B/lane, wave-uniform LDS base) ----------
__device__ __forceinline__ void gload16(const void* g, void* l) {
  __builtin_amdgcn_global_load_lds(
      (const __attribute__((address_space(1))) uint32_t*)g,
      (__attribute__((address_space(3))) uint32_t*)l, 16, 0, 0);
}

__device__ __forceinline__ void bar()  { __builtin_amdgcn_s_barrier(); }
__device__ __forceinline__ void sbar() { asm volatile("s_barrier" ::: "memory"); }

// ---------- conversion kernels ----------
__global__ void cvt_x_k(const float* __restrict__ x, unsigned short* __restrict__ xb) {
  int i = blockIdx.x * blockDim.x + threadIdx.x;
  int k8 = i & 127;
  int bt = i >> 7;
  int b = bt / 5, t = bt - b * 5;
  const f32x4* s = (const f32x4*)(x + (size_t)bt * 1024 + (size_t)k8 * 8);
  unsigned short* d = xb + ((size_t)t * 4096 + b) * 1024 + (size_t)k8 * 8;
  f32x4 a = s[0], c = s[1];
  short8 o;
#pragma unroll
  for (int j = 0; j < 4; ++j) { o[j] = (short)f2bf(a[j]); o[4 + j] = (short)f2bf(c[j]); }
  *(short8*)d = o;
}

__global__ void cvt_w_k(const float* __restrict__ src, unsigned short* __restrict__ dst, int n8) {
  int i = blockIdx.x * blockDim.x + threadIdx.x;
  if (i >= n8) return;
  const f32x4* s = (const f32x4*)src + (size_t)i * 2;
  f32x4 a = s[0], c = s[1];
  short8 o;
#pragma unroll
  for (int j = 0; j < 4; ++j) { o[j] = (short)f2bf(a[j]); o[4 + j] = (short)f2bf(c[j]); }
  *(short8*)(dst + (size_t)i * 8) = o;
}

// ============================================================================
// 8-phase 256x256 GEMM (C = A @ W^T + b) + fused LIF.  BK=64, 8 waves (2Mx4N),
// 512 threads.  LDS: ring of 10 half-tile slots (16 KB each = 128 rows x 64
// cols bf16), full 160 KB.  Granule swizzle: phys_gc = gc ^ (row & 7), applied
// on BOTH the staging global source and the ds_read address (LDS dest linear).
// Tile t reads slots sb..sb+3 (A0,A1,B0,B1); its phases issue t+1.B0/B1 and
// t+2.A0/A1 into slots sb+6..sb+9 (always disjoint).  One counted vmcnt(4)
// per K-tile; 4 loads stay in flight across every barrier.
// ============================================================================
template <bool FIRST, int LAYER>
__global__ __launch_bounds__(512, 2) void gemm_lif8(
    const unsigned short* __restrict__ A, const unsigned short* __restrict__ W,
    const float* __restrict__ bias,
    float* __restrict__ mem, unsigned short* __restrict__ sbuf,
    float* __restrict__ outacc,
    int M, int N, int K, int nbn)
{
  __shared__ __align__(16) unsigned short lds[10 * 8192];   // 160 KiB

  const int tid  = threadIdx.x;
  const int lane = tid & 63;
  const int wid  = tid >> 6;
  const int wr = wid >> 2, wc = wid & 3;

  // XCD-aware swizzle (grid multiple of 8)
  const int nwg = gridDim.x;
  const int cpx = nwg >> 3;
  const int bid = blockIdx.x;
  const int swz = (bid & 7) * cpx + (bid >> 3);
  const int bm = swz / nbn, bn = swz % nbn;
  const int bmr = bm * 256, bnr = bn * 256;

  // ---- compute-side LDS read offsets (elements) ----
  const int l15 = lane & 15, l7 = lane & 7, lk = lane >> 4;
  const int aoff0 = l15 * 64 + ((lk)     ^ l7) * 8;   // ksub 0 (k 0..31)
  const int aoff1 = l15 * 64 + ((4 + lk) ^ l7) * 8;   // ksub 1 (k 32..63)
  const int bhoff = (wc & 1) * 4096;                  // 64 rows into the B-half

  // ---- staging-side constants ----
  const int srs = lane >> 3;               // sub-row 0..7 within 8-row chunk
  const int sgc = (lane & 7) ^ srs;        // logical granule this lane fetches
  const int ldst = wid * 1024;             // LDS elem offset of this wave's chunk

  const unsigned short* gAt = A + (size_t)(bmr + wid * 16 + srs) * K + sgc * 8;
  const unsigned short* gBt = W + (size_t)(bnr + wid * 16 + srs) * K + sgc * 8;
  const size_t rK8   = (size_t)8 * K;      // +8 rows
  const size_t rK128 = (size_t)128 * K;    // +half

  auto stA = [&](int slot, int hh, int kt) {
    const unsigned short* g = gAt + (size_t)hh * rK128 + (size_t)kt * 64;
    unsigned short* d = &lds[slot * 8192 + ldst];
    gload16(g, d);
    gload16(g + rK8, d + 512);
  };
  auto stB = [&](int slot, int hh, int kt) {
    const unsigned short* g = gBt + (size_t)hh * rK128 + (size_t)kt * 64;
    unsigned short* d = &lds[slot * 8192 + ldst];
    gload16(g, d);
    gload16(g + rK8, d + 512);
  };

  f32x4 acc[8][4];
#pragma unroll
  for (int m = 0; m < 8; ++m)
#pragma unroll
    for (int n = 0; n < 4; ++n) acc[m][n] = (f32x4){0.f, 0.f, 0.f, 0.f};

  const int nkt = K >> 6;

  // ---- prologue: tile0 complete + tile1 A-halves; keep t1.A in flight ----
  stA(0, 0, 0); stA(1, 1, 0); stB(2, 0, 0); stB(3, 1, 0);
  if (nkt > 1) {
    stA(4, 0, 1); stA(5, 1, 1);
    asm volatile("s_waitcnt vmcnt(4)" ::: "memory");
  } else {
    asm volatile("s_waitcnt vmcnt(0)" ::: "memory");
  }
  sbar();
  __builtin_amdgcn_sched_barrier(0);

  int sb = 0;
  for (int t = 0; t < nkt; ++t) {
    int sA = sb + wr;             if (sA >= 10) sA -= 10;
    int sBs = sb + 2 + (wc >> 1); if (sBs >= 10) sBs -= 10;
    const unsigned short* ab = &lds[sA * 8192];
    const unsigned short* bb = &lds[sBs * 8192] + bhoff;
    const bool p1 = (t + 1 < nkt), p2 = (t + 2 < nkt);
    int s6 = sb + 6; if (s6 >= 10) s6 -= 10;
    int s7 = sb + 7; if (s7 >= 10) s7 -= 10;
    int s8 = sb + 8; if (s8 >= 10) s8 -= 10;
    int s9 = sb + 9; if (s9 >= 10) s9 -= 10;

    short8 afl[4], afh[4], bf0[4], bf1[4];

    // ---- P1: A-lo k0 + B k0 ----
#pragma unroll
    for (int m = 0; m < 4; ++m) afl[m] = *(const short8*)(ab + m * 1024 + aoff0);
#pragma unroll
    for (int n = 0; n < 4; ++n) bf0[n] = *(const short8*)(bb + n * 1024 + aoff0);
    if (p1) stB(s6, 0, t + 1);
    bar();
    __builtin_amdgcn_s_setprio(1);
#pragma unroll
    for (int m = 0; m < 4; ++m)
#pragma unroll
      for (int n = 0; n < 4; ++n)
        acc[m][n] = __builtin_amdgcn_mfma_f32_16x16x32_bf16(afl[m], bf0[n], acc[m][n], 0, 0, 0);
    __builtin_amdgcn_s_setprio(0);
    bar();

    // ---- P2: A-hi k0 ----
#pragma unroll
    for (int m = 0; m < 4; ++m) afh[m] = *(const short8*)(ab + (4 + m) * 1024 + aoff0);
    if (p1) stB(s7, 1, t + 1);
    bar();
    __builtin_amdgcn_s_setprio(1);
#pragma unroll
    for (int m = 0; m < 4; ++m)
#pragma unroll
      for (int n = 0; n < 4; ++n)
        acc[4 + m][n] = __builtin_amdgcn_mfma_f32_16x16x32_bf16(afh[m], bf0[n], acc[4 + m][n], 0, 0, 0);
    __builtin_amdgcn_s_setprio(0);
    bar();

    // ---- P3: A-lo k1 + B k1 ----
#pragma unroll
    for (int m = 0; m < 4; ++m) afl[m] = *(const short8*)(ab + m * 1024 + aoff1);
#pragma unroll
    for (int n = 0; n < 4; ++n) bf1[n] = *(const short8*)(bb + n * 1024 + aoff1);
    if (p2) stA(s8, 0, t + 2);
    bar();
    __builtin_amdgcn_s_setprio(1);
#pragma unroll
    for (int m = 0; m < 4; ++m)
#pragma unroll
      for (int n = 0; n < 4; ++n)
        acc[m][n] = __builtin_amdgcn_mfma_f32_16x16x32_bf16(afl[m], bf1[n], acc[m][n], 0, 0, 0);
    __builtin_amdgcn_s_setprio(0);
    bar();

    // ---- P4: A-hi k1 ----
#pragma unroll
    for (int m = 0; m < 4; ++m) afh[m] = *(const short8*)(ab + (4 + m) * 1024 + aoff1);
    if (p2) stA(s9, 1, t + 2);
    bar();
    __builtin_amdgcn_s_setprio(1);
#pragma unroll
    for (int m = 0; m < 4; ++m)
#pragma unroll
      for (int n = 0; n < 4; ++n)
        acc[4 + m][n] = __builtin_amdgcn_mfma_f32_16x16x32_bf16(afh[m], bf1[n], acc[4 + m][n], 0, 0, 0);
    __builtin_amdgcn_s_setprio(0);

    // tile-boundary: complete t+1's halves, keep t+2.A0/A1 (4 loads) flying
    if (p2)      asm volatile("s_waitcnt vmcnt(4)" ::: "memory");
    else if (p1) asm volatile("s_waitcnt vmcnt(0)" ::: "memory");
    sbar();
    __builtin_amdgcn_sched_barrier(0);

    sb += 4; if (sb >= 10) sb -= 10;
  }

  // ---- LIF epilogue.  C/D: col = lane&15, row = (lane>>4)*4 + j ----
  const int crow0 = bmr + wr * 128;
  const int ccol0 = bnr + wc * 64;
  float bcol[4];
#pragma unroll
  for (int n = 0; n < 4; ++n) bcol[n] = bias[ccol0 + n * 16 + l15];
#pragma unroll
  for (int m = 0; m < 8; ++m) {
#pragma unroll
    for (int n = 0; n < 4; ++n) {
      const int col = ccol0 + n * 16 + l15;
#pragma unroll
      for (int j = 0; j < 4; ++j) {
        const int row = crow0 + m * 16 + lk * 4 + j;
        const size_t idx = (size_t)row * N + col;
        const float curv = acc[m][n][j] + bcol[n];
        const float mold = FIRST ? 0.f : mem[idx];
        const float sprv = FIRST ? 0.f : bf2f(sbuf[idx]);
        const float mnew = BETA * mold + curv - sprv;
        mem[idx] = mnew;
        const float s = (mnew - 1.0f) > 0.f ? 1.f : 0.f;
        sbuf[idx] = f2bf(s);
        if (LAYER == 3) outacc[idx] = FIRST ? s : (outacc[idx] + s);
      }
    }
  }
}

// ============================================================================
// Round-0 128x128 kernel (kept for layer 3: N=1024 grid is 256 blocks here)
// ============================================================================
template <bool FIRST, int LAYER>
__global__ __launch_bounds__(256, 2) void gemm_lif(
    const unsigned short* __restrict__ A, const unsigned short* __restrict__ W,
    const float* __restrict__ bias,
    float* __restrict__ mem, unsigned short* __restrict__ sbuf,
    float* __restrict__ outacc,
    int M, int N, int K)
{
  __shared__ __align__(16) unsigned short As[2][128 * 32];
  __shared__ __align__(16) unsigned short Bs[2][128 * 32];

  const int tid  = threadIdx.x;
  const int wid  = tid >> 6;
  const int lane = tid & 63;
  const int bm = blockIdx.x, bn = blockIdx.y;
  const int wr = wid >> 1, wc = wid & 1;
  const int krow = lane >> 2;
  const int kcol = (lane & 3) << 3;

  f32x4 acc[4][4];
#pragma unroll
  for (int m = 0; m < 4; ++m)
#pragma unroll
    for (int n = 0; n < 4; ++n) acc[m][n] = (f32x4){0.f, 0.f, 0.f, 0.f};

  const unsigned short* gA = A + (size_t)bm * 128 * K;
  const unsigned short* gB = W + (size_t)bn * 128 * K;
  const int r0 = wid * 32;

  auto stage = [&](int buf, int kt) {
    const unsigned short* ga = gA + (size_t)kt * 32;
    const unsigned short* gb = gB + (size_t)kt * 32;
#pragma unroll
    for (int c = 0; c < 2; ++c) {
      int row0 = r0 + c * 16;
      gload16(ga + (size_t)(row0 + krow) * K + kcol, &As[buf][row0 * 32]);
      gload16(gb + (size_t)(row0 + krow) * K + kcol, &Bs[buf][row0 * 32]);
    }
  };

  auto compute = [&](int buf) {
    short8 af[4], bfr[4];
    const int ar = wr * 64 + (lane & 15);
    const int br = wc * 64 + (lane & 15);
    const int kseg = (lane >> 4) * 8;
#pragma unroll
    for (int m = 0; m < 4; ++m)
      af[m] = *(const short8*)&As[buf][(ar + m * 16) * 32 + kseg];
#pragma unroll
    for (int n = 0; n < 4; ++n)
      bfr[n] = *(const short8*)&Bs[buf][(br + n * 16) * 32 + kseg];
#pragma unroll
    for (int m = 0; m < 4; ++m)
#pragma unroll
      for (int n = 0; n < 4; ++n)
        acc[m][n] = __builtin_amdgcn_mfma_f32_16x16x32_bf16(af[m], bfr[n], acc[m][n], 0, 0, 0);
  };

  const int nkt = K >> 5;
  stage(0, 0);
  __syncthreads();
  int cur = 0;
  for (int kt = 1; kt < nkt; ++kt) {
    stage(cur ^ 1, kt);
    compute(cur);
    __syncthreads();
    cur ^= 1;
  }
  compute(cur);

  const int crow0 = bm * 128 + wr * 64;
  const int ccol0 = bn * 128 + wc * 64;
#pragma unroll
  for (int m = 0; m < 4; ++m) {
#pragma unroll
    for (int n = 0; n < 4; ++n) {
      const int col = ccol0 + n * 16 + (lane & 15);
      const float bcol = bias[col];
#pragma unroll
      for (int j = 0; j < 4; ++j) {
        const int row = crow0 + m * 16 + (lane >> 4) * 4 + j;
        const size_t idx = (size_t)row * N + col;
        const float curv = acc[m][n][j] + bcol;
        const float mold = FIRST ? 0.f : mem[idx];
        const float sprv = FIRST ? 0.f : bf2f(sbuf[idx]);
        const float mnew = BETA * mold + curv - sprv;
        mem[idx] = mnew;
        const float s = (mnew - 1.0f) > 0.f ? 1.f : 0.f;
        sbuf[idx] = f2bf(s);
        if (LAYER == 3) outacc[idx] = FIRST ? s : (outacc[idx] + s);
      }
    }
  }
}

// ---------- host ----------
extern "C" void kernel_launch(void* const* d_in, const int* in_sizes, int n_in,
                              void* d_out, int out_size, void* d_ws, size_t ws_size,
                              hipStream_t stream)
{
  const float* x  = (const float*)d_in[0];
  const float* W1 = (const float*)d_in[1];
  const float* b1 = (const float*)d_in[2];
  const float* W2 = (const float*)d_in[3];
  const float* b2 = (const float*)d_in[4];
  const float* W3 = (const float*)d_in[5];
  const float* b3 = (const float*)d_in[6];
  float* out = (float*)d_out;

  char* p = (char*)d_ws;
  auto wsalloc = [&](size_t bytes) { char* r = p; p += (bytes + 255) & ~(size_t)255; return r; };
  unsigned short* xb   = (unsigned short*)wsalloc((size_t)5 * 4096 * 1024 * 2);
  unsigned short* W1b  = (unsigned short*)wsalloc((size_t)4096 * 1024 * 2);
  unsigned short* W2b  = (unsigned short*)wsalloc((size_t)4096 * 4096 * 2);
  unsigned short* W3b  = (unsigned short*)wsalloc((size_t)1024 * 4096 * 2);
  unsigned short* s1   = (unsigned short*)wsalloc((size_t)4096 * 4096 * 2);
  unsigned short* s2   = (unsigned short*)wsalloc((size_t)4096 * 4096 * 2);
  unsigned short* s3   = (unsigned short*)wsalloc((size_t)4096 * 1024 * 2);
  float* mem1 = (float*)wsalloc((size_t)4096 * 4096 * 4);
  float* mem2 = (float*)wsalloc((size_t)4096 * 4096 * 4);
  float* mem3 = (float*)wsalloc((size_t)4096 * 1024 * 4);

  cvt_x_k<<<dim3(4096 * 5 * 128 / 256), dim3(256), 0, stream>>>(x, xb);
  cvt_w_k<<<dim3(4096 * 1024 / 8 / 256), dim3(256), 0, stream>>>(W1, W1b, 4096 * 1024 / 8);
  cvt_w_k<<<dim3(4096 * 4096 / 8 / 256), dim3(256), 0, stream>>>(W2, W2b, 4096 * 4096 / 8);
  cvt_w_k<<<dim3(1024 * 4096 / 8 / 256), dim3(256), 0, stream>>>(W3, W3b, 1024 * 4096 / 8);

  const dim3 blk8(512), blk(256);
  const dim3 g8(256);       // (4096/256)*(4096/256), nbn=16
  const dim3 g3(32, 8);     // layer 3: 128x128 tiles

  gemm_lif8<true, 1><<<g8, blk8, 0, stream>>>(xb, W1b, b1, mem1, s1, nullptr, 4096, 4096, 1024, 16);
  gemm_lif8<true, 2><<<g8, blk8, 0, stream>>>(s1, W2b, b2, mem2, s2, nullptr, 4096, 4096, 4096, 16);
  gemm_lif<true, 3><<<g3, blk, 0, stream>>>(s2, W3b, b3, mem3, s3, out, 4096, 1024, 4096);
  for (int t = 1; t < 5; ++t) {
    gemm_lif8<false, 1><<<g8, blk8, 0, stream>>>(xb + (size_t)t * 4096 * 1024, W1b, b1, mem1, s1, nullptr, 4096, 4096, 1024, 16);
    gemm_lif8<false, 2><<<g8, blk8, 0, stream>>>(s1, W2b, b2, mem2, s2, nullptr, 4096, 4096, 4096, 16);
    gemm_lif<false, 3><<<g3, blk, 0, stream>>>(s2, W3b, b3, mem3, s3, out, 4096, 1024, 4096);
  }
}